// Round 2
// baseline (488.303 us; speedup 1.0000x reference)
//
#include <hip/hip_runtime.h>
#include <hip/hip_bf16.h>

#define BATCH 8
#define CIN   64
#define COUT  64
#define HH    32
#define WW    64
#define NN    2048   // HH*WW
#define TI    8      // query rows per attention block

// ---------------------------------------------------------------------------
// Kernel 1: three 3x3 SAME convs (q, k, v). blockIdx.z selects which.
// Each thread: 1 pixel x 8 output channels. q,k stored [b][c][n]; v stored
// transposed [b][n][c] so the PV phase reads coalesced.
// ---------------------------------------------------------------------------
__global__ __launch_bounds__(256) void conv_qkv(
    const float* __restrict__ x,
    const float* __restrict__ wq, const float* __restrict__ bq,
    const float* __restrict__ wk, const float* __restrict__ bk,
    const float* __restrict__ wv, const float* __restrict__ bv,
    float* __restrict__ q, float* __restrict__ k, float* __restrict__ vT)
{
    const int which = blockIdx.z;
    const float* __restrict__ wgt  = (which == 0) ? wq : (which == 1) ? wk : wv;
    const float* __restrict__ bias = (which == 0) ? bq : (which == 1) ? bk : bv;

    const int bid  = blockIdx.x;        // 0..511
    const int bi   = bid >> 6;          // batch
    const int rem  = bid & 63;
    const int pblk = rem >> 3;          // pixel block (8 x 256 = 2048 pixels)
    const int cog  = rem & 7;           // channel group (8 groups of 8)
    const int co0  = cog * 8;
    const int p    = pblk * 256 + threadIdx.x;
    const int y    = p >> 6;
    const int xx   = p & 63;

    float acc[8];
#pragma unroll
    for (int u = 0; u < 8; ++u) acc[u] = bias[co0 + u];

    const float* __restrict__ xb = x + (size_t)bi * CIN * HH * WW;

    for (int ci = 0; ci < CIN; ++ci) {
        const float* __restrict__ xc = xb + ci * (HH * WW);
        const float* __restrict__ wc = wgt + ((size_t)co0 * CIN + ci) * 9;
#pragma unroll
        for (int ky = 0; ky < 3; ++ky) {
            const int yy = y + ky - 1;
            if (yy < 0 || yy >= HH) continue;
            const float* __restrict__ xr = xc + yy * WW;
#pragma unroll
            for (int kx = 0; kx < 3; ++kx) {
                const int x2 = xx + kx - 1;
                if (x2 < 0 || x2 >= WW) continue;
                const float xv = xr[x2];
#pragma unroll
                for (int u = 0; u < 8; ++u)
                    acc[u] = fmaf(xv, wc[(size_t)u * (CIN * 9) + ky * 3 + kx], acc[u]);
            }
        }
    }

    if (which == 0) {
#pragma unroll
        for (int u = 0; u < 8; ++u)
            q[((size_t)bi * COUT + co0 + u) * NN + p] = acc[u];
    } else if (which == 1) {
#pragma unroll
        for (int u = 0; u < 8; ++u)
            k[((size_t)bi * COUT + co0 + u) * NN + p] = acc[u];
    } else {
#pragma unroll
        for (int u = 0; u < 8; ++u)
            vT[((size_t)bi * NN + p) * COUT + co0 + u] = acc[u];
    }
}

// ---------------------------------------------------------------------------
// Kernel 2: attention. One block per (batch, TI-row tile). Scores tile kept in
// LDS as S[j][ii] (64 KB). fp32 throughout; f32 output (reference dtype).
// ---------------------------------------------------------------------------
__global__ __launch_bounds__(256) void attn_kernel(
    const float* __restrict__ q, const float* __restrict__ k,
    const float* __restrict__ vT, float* __restrict__ out)
{
    __shared__ float S[NN][TI];          // 64 KB: S[j][ii]
    __shared__ float qs[COUT][TI];       // 2 KB
    __shared__ float red[4][TI];         // wave partials
    __shared__ float red2[4][COUT][TI];  // 8 KB: PV partials per group

    const int bi  = blockIdx.x >> 8;     // batch
    const int it  = blockIdx.x & 255;    // tile index
    const int i0  = it * TI;
    const int tid = threadIdx.x;
    const int lane = tid & 63;
    const int wave = tid >> 6;

    // ---- load Q tile into LDS ----
    for (int t = tid; t < COUT * TI; t += 256) {
        const int c = t >> 3, ii = t & 7;
        qs[c][ii] = q[((size_t)bi * COUT + c) * NN + i0 + ii];
    }
    __syncthreads();

    // ---- Phase 1: S[j][ii] = sum_c qs[c][ii] * k[c][j] ----
    const float* __restrict__ kb = k + (size_t)bi * COUT * NN;
    for (int jj = 0; jj < NN / 256; ++jj) {
        const int j = jj * 256 + tid;
        float s[TI];
#pragma unroll
        for (int ii = 0; ii < TI; ++ii) s[ii] = 0.0f;
#pragma unroll 4
        for (int c = 0; c < COUT; ++c) {
            const float kv = kb[(size_t)c * NN + j];
#pragma unroll
            for (int ii = 0; ii < TI; ++ii)
                s[ii] = fmaf(kv, qs[c][ii], s[ii]);
        }
#pragma unroll
        for (int ii = 0; ii < TI; ++ii) S[j][ii] = s[ii];
    }
    __syncthreads();

    // ---- Phase 2: softmax over j for each of the TI rows ----
    float e[8][TI];          // this thread's 8 j-slots x TI rows
    float mx[TI];
#pragma unroll
    for (int ii = 0; ii < TI; ++ii) mx[ii] = -1e30f;
#pragma unroll
    for (int jj = 0; jj < 8; ++jj) {
        const int j = jj * 256 + tid;
#pragma unroll
        for (int ii = 0; ii < TI; ++ii) {
            e[jj][ii] = S[j][ii];
            mx[ii] = fmaxf(mx[ii], e[jj][ii]);
        }
    }
    // wave max
#pragma unroll
    for (int ii = 0; ii < TI; ++ii) {
        float m = mx[ii];
#pragma unroll
        for (int off = 32; off > 0; off >>= 1)
            m = fmaxf(m, __shfl_xor(m, off));
        mx[ii] = m;
    }
    if (lane == 0) {
#pragma unroll
        for (int ii = 0; ii < TI; ++ii) red[wave][ii] = mx[ii];
    }
    __syncthreads();
#pragma unroll
    for (int ii = 0; ii < TI; ++ii)
        mx[ii] = fmaxf(fmaxf(red[0][ii], red[1][ii]), fmaxf(red[2][ii], red[3][ii]));
    __syncthreads();   // everyone done reading red before reuse

    float sm[TI];
#pragma unroll
    for (int ii = 0; ii < TI; ++ii) sm[ii] = 0.0f;
#pragma unroll
    for (int jj = 0; jj < 8; ++jj) {
#pragma unroll
        for (int ii = 0; ii < TI; ++ii) {
            e[jj][ii] = __expf(e[jj][ii] - mx[ii]);
            sm[ii] += e[jj][ii];
        }
    }
#pragma unroll
    for (int ii = 0; ii < TI; ++ii) {
        float sv = sm[ii];
#pragma unroll
        for (int off = 32; off > 0; off >>= 1)
            sv += __shfl_xor(sv, off);
        sm[ii] = sv;
    }
    if (lane == 0) {
#pragma unroll
        for (int ii = 0; ii < TI; ++ii) red[wave][ii] = sm[ii];
    }
    __syncthreads();
    float inv[TI];
#pragma unroll
    for (int ii = 0; ii < TI; ++ii) {
        const float l = red[0][ii] + red[1][ii] + red[2][ii] + red[3][ii];
        inv[ii] = 1.0f / l;
    }
    // write probabilities back (each thread rewrites only its own j slots)
#pragma unroll
    for (int jj = 0; jj < 8; ++jj) {
        const int j = jj * 256 + tid;
#pragma unroll
        for (int ii = 0; ii < TI; ++ii) S[j][ii] = e[jj][ii] * inv[ii];
    }
    __syncthreads();

    // ---- Phase 3: out[c][i0+ii] = sum_j P[j][ii] * vT[j][c] ----
    const int c = tid & 63;
    const int g = tid >> 6;              // 4 j-range groups
    const float* __restrict__ vb = vT + (size_t)bi * NN * COUT;
    float acc[TI];
#pragma unroll
    for (int ii = 0; ii < TI; ++ii) acc[ii] = 0.0f;
    const int j0 = g * (NN / 4);
#pragma unroll 4
    for (int jt = 0; jt < NN / 4; ++jt) {
        const int j = j0 + jt;
        const float vv = vb[(size_t)j * COUT + c];
#pragma unroll
        for (int ii = 0; ii < TI; ++ii)
            acc[ii] = fmaf(S[j][ii], vv, acc[ii]);
    }
#pragma unroll
    for (int ii = 0; ii < TI; ++ii) red2[g][c][ii] = acc[ii];
    __syncthreads();

    for (int t = tid; t < COUT * TI; t += 256) {
        const int c2 = t >> 3, ii = t & 7;
        const float v = red2[0][c2][ii] + red2[1][c2][ii] +
                        red2[2][c2][ii] + red2[3][c2][ii];
        out[((size_t)bi * COUT + c2) * NN + i0 + ii] = v;   // f32 store (ref dtype)
    }
}

// ---------------------------------------------------------------------------
extern "C" void kernel_launch(void* const* d_in, const int* in_sizes, int n_in,
                              void* d_out, int out_size, void* d_ws, size_t ws_size,
                              hipStream_t stream)
{
    const float* x  = (const float*)d_in[0];
    const float* wq = (const float*)d_in[1];
    const float* bq = (const float*)d_in[2];
    const float* wk = (const float*)d_in[3];
    const float* bk = (const float*)d_in[4];
    const float* wv = (const float*)d_in[5];
    const float* bv = (const float*)d_in[6];

    float* ws = (float*)d_ws;
    float* q  = ws;                                // 8*64*2048 floats = 4 MB
    float* k  = ws + (size_t)BATCH * COUT * NN;    // 4 MB
    float* vT = ws + (size_t)2 * BATCH * COUT * NN;// 4 MB, layout [b][n][c]
    float* out = (float*)d_out;

    dim3 gridc(512, 1, 3);
    conv_qkv<<<gridc, 256, 0, stream>>>(x, wq, bq, wk, bk, wv, bv, q, k, vT);

    attn_kernel<<<dim3(BATCH * (NN / TI)), 256, 0, stream>>>(q, k, vT, out);
}

// Round 3
// 182.916 us; speedup vs baseline: 2.6696x; 2.6696x over previous
//
#include <hip/hip_runtime.h>
#include <hip/hip_bf16.h>

#define BATCH 8
#define CIN   64
#define NC    64      // channels (Cin == Cout == 64)
#define HH    32
#define WW    64
#define NN    2048    // HH*WW

typedef __attribute__((ext_vector_type(8))) short bf16x8;
typedef __attribute__((ext_vector_type(4))) short short4v;
typedef __attribute__((ext_vector_type(4))) float f32x4;

__device__ __forceinline__ unsigned short f2bf(float f) {
    union { float f; unsigned u; } v; v.f = f;
    unsigned r = v.u + 0x7fffu + ((v.u >> 16) & 1u);   // RNE
    return (unsigned short)(r >> 16);
}

__device__ __forceinline__ bf16x8 load8(const unsigned short* a, const unsigned short* b) {
    short4v lo = *(const short4v*)a;
    short4v hi = *(const short4v*)b;
    return __builtin_shufflevector(lo, hi, 0, 1, 2, 3, 4, 5, 6, 7);
}

// ---------------------------------------------------------------------------
// Kernel 1: three 3x3 SAME convs (fp32 math). Outputs bf16:
//   q -> qT [b][n][c], k -> kT [b][n][c], v -> v [b][c][n]
// ---------------------------------------------------------------------------
__global__ __launch_bounds__(256) void conv_qkv(
    const float* __restrict__ x,
    const float* __restrict__ wq, const float* __restrict__ bq,
    const float* __restrict__ wk, const float* __restrict__ bk,
    const float* __restrict__ wv, const float* __restrict__ bv,
    unsigned short* __restrict__ qT, unsigned short* __restrict__ kT,
    unsigned short* __restrict__ vv)
{
    const int which = blockIdx.z;
    const float* __restrict__ wgt  = (which == 0) ? wq : (which == 1) ? wk : wv;
    const float* __restrict__ bias = (which == 0) ? bq : (which == 1) ? bk : bv;

    const int bid  = blockIdx.x;        // 0..511
    const int bi   = bid >> 6;          // batch
    const int rem  = bid & 63;
    const int pblk = rem >> 3;          // pixel block
    const int cog  = rem & 7;           // channel group
    const int co0  = cog * 8;
    const int p    = pblk * 256 + threadIdx.x;
    const int y    = p >> 6;
    const int xx   = p & 63;

    float acc[8];
#pragma unroll
    for (int u = 0; u < 8; ++u) acc[u] = bias[co0 + u];

    const float* __restrict__ xb = x + (size_t)bi * CIN * HH * WW;

    for (int ci = 0; ci < CIN; ++ci) {
        const float* __restrict__ xc = xb + ci * (HH * WW);
        const float* __restrict__ wc = wgt + ((size_t)co0 * CIN + ci) * 9;
#pragma unroll
        for (int ky = 0; ky < 3; ++ky) {
            const int yy = y + ky - 1;
            if (yy < 0 || yy >= HH) continue;
            const float* __restrict__ xr = xc + yy * WW;
#pragma unroll
            for (int kx = 0; kx < 3; ++kx) {
                const int x2 = xx + kx - 1;
                if (x2 < 0 || x2 >= WW) continue;
                const float xv = xr[x2];
#pragma unroll
                for (int u = 0; u < 8; ++u)
                    acc[u] = fmaf(xv, wc[(size_t)u * (CIN * 9) + ky * 3 + kx], acc[u]);
            }
        }
    }

    if (which == 2) {
        // v[b][c][n]: per-u store is 128B-contiguous across the wave
#pragma unroll
        for (int u = 0; u < 8; ++u)
            vv[((size_t)bi * NC + co0 + u) * NN + p] = f2bf(acc[u]);
    } else {
        unsigned short h[8];
#pragma unroll
        for (int u = 0; u < 8; ++u) h[u] = f2bf(acc[u]);
        uint4 wv4;
        wv4.x = (unsigned)h[0] | ((unsigned)h[1] << 16);
        wv4.y = (unsigned)h[2] | ((unsigned)h[3] << 16);
        wv4.z = (unsigned)h[4] | ((unsigned)h[5] << 16);
        wv4.w = (unsigned)h[6] | ((unsigned)h[7] << 16);
        unsigned short* dst = ((which == 0) ? qT : kT) + ((size_t)bi * NN + p) * NC + co0;
        *(uint4*)dst = wv4;
    }
}

// ---------------------------------------------------------------------------
// Kernel 2: bf16 MFMA flash attention.
// Block = 4 waves; wave w owns 16 query rows. 64 j-tiles of 32 columns.
// Swapped QK^T: S^T = mfma(Kfrag, Qfrag) puts row i = lane&15 lane-local;
// packed P chains directly into the PV MFMA A-operand.
// ---------------------------------------------------------------------------
__global__ __launch_bounds__(256) void attn_mfma(
    const unsigned short* __restrict__ qT,  // [b][n][c]
    const unsigned short* __restrict__ kT,  // [b][n][c]
    const unsigned short* __restrict__ vv,  // [b][c][n]
    float* __restrict__ out)                // [b][c][n]
{
    __shared__ __align__(16) unsigned short Qs[64][72];
    __shared__ __align__(16) unsigned short Ks[2][32][72];
    __shared__ __align__(16) unsigned short Vs[2][64][40];
    __shared__ __align__(16) float Os[4][16][66];

    const int bi   = blockIdx.x >> 5;    // batch
    const int blki = blockIdx.x & 31;    // 64-row tile within batch
    const int tid  = threadIdx.x;
    const int l    = tid & 63;
    const int w    = tid >> 6;
    const int g    = l >> 4;
    const int li   = l & 15;

    const unsigned short* qb = qT + (size_t)bi * NN * NC;
    const unsigned short* kb = kT + (size_t)bi * NN * NC;
    const unsigned short* vb = vv + (size_t)bi * NC * NN;

    // ---- stage Q tile (64 rows x 64 c) ----
    {
        const int r0 = tid >> 3;        // 0..31
        const int ch = tid & 7;
#pragma unroll
        for (int pass = 0; pass < 2; ++pass) {
            const int r = pass * 32 + r0;
            uint4 d = *(const uint4*)(qb + ((size_t)(blki * 64 + r)) * NC + ch * 8);
            *(uint4*)&Qs[r][ch * 8] = d;
        }
    }

    // ---- prologue: stage j-tile 0 ----
    uint4 kd, vd;
    {
        kd = *(const uint4*)(kb + ((size_t)(tid >> 3)) * NC + (tid & 7) * 8);
        vd = *(const uint4*)(vb + (size_t)(tid >> 2) * NN + (tid & 3) * 8);
        *(uint4*)&Ks[0][tid >> 3][(tid & 7) * 8] = kd;
        *(uint4*)&Vs[0][tid >> 2][(tid & 3) * 8] = vd;
    }
    __syncthreads();

    // ---- Q fragments (hoisted) ----
    const int qrow = w * 16 + li;
    const bf16x8 qf0 = load8(&Qs[qrow][4 * g],      &Qs[qrow][16 + 4 * g]);
    const bf16x8 qf1 = load8(&Qs[qrow][32 + 4 * g], &Qs[qrow][48 + 4 * g]);

    f32x4 o0 = {0,0,0,0}, o1 = {0,0,0,0}, o2 = {0,0,0,0}, o3 = {0,0,0,0};
    float m = -1e30f, lsum = 0.0f;

    for (int t = 0; t < 64; ++t) {
        const int cur = t & 1;
        if (t < 63) {
            const int j0 = (t + 1) * 32;
            kd = *(const uint4*)(kb + ((size_t)(j0 + (tid >> 3))) * NC + (tid & 7) * 8);
            vd = *(const uint4*)(vb + (size_t)(tid >> 2) * NN + j0 + (tid & 3) * 8);
        }

        // K fragments (rows = j within tile)
        const bf16x8 kf00 = load8(&Ks[cur][li][4 * g],           &Ks[cur][li][16 + 4 * g]);
        const bf16x8 kf01 = load8(&Ks[cur][li][32 + 4 * g],      &Ks[cur][li][48 + 4 * g]);
        const bf16x8 kf10 = load8(&Ks[cur][16 + li][4 * g],      &Ks[cur][16 + li][16 + 4 * g]);
        const bf16x8 kf11 = load8(&Ks[cur][16 + li][32 + 4 * g], &Ks[cur][16 + li][48 + 4 * g]);

        const f32x4 z = {0,0,0,0};
        f32x4 d0 = __builtin_amdgcn_mfma_f32_16x16x32_bf16(kf00, qf0, z, 0, 0, 0);
        d0       = __builtin_amdgcn_mfma_f32_16x16x32_bf16(kf01, qf1, d0, 0, 0, 0);
        f32x4 d1 = __builtin_amdgcn_mfma_f32_16x16x32_bf16(kf10, qf0, z, 0, 0, 0);
        d1       = __builtin_amdgcn_mfma_f32_16x16x32_bf16(kf11, qf1, d1, 0, 0, 0);

        // ---- online softmax (row i = lane&15 is lane-local) ----
        float pmax = fmaxf(fmaxf(fmaxf(d0[0], d0[1]), fmaxf(d0[2], d0[3])),
                           fmaxf(fmaxf(d1[0], d1[1]), fmaxf(d1[2], d1[3])));
        pmax = fmaxf(pmax, __shfl_xor(pmax, 16));
        pmax = fmaxf(pmax, __shfl_xor(pmax, 32));
        const float mn = fmaxf(m, pmax);
        const float alpha = __expf(m - mn);
        m = mn;

        float p[8];
#pragma unroll
        for (int e = 0; e < 4; ++e) {
            p[e]     = __expf(d0[e] - mn);
            p[4 + e] = __expf(d1[e] - mn);
        }
        float ls = ((p[0] + p[1]) + (p[2] + p[3])) + ((p[4] + p[5]) + (p[6] + p[7]));
        ls += __shfl_xor(ls, 16);
        ls += __shfl_xor(ls, 32);
        lsum = lsum * alpha + ls;

        // rescale O (O rows are i = 4g+r -> fetch alpha for that row)
#pragma unroll
        for (int r = 0; r < 4; ++r) {
            const float ar = __shfl(alpha, 4 * g + r, 16);
            o0[r] *= ar; o1[r] *= ar; o2[r] *= ar; o3[r] *= ar;
        }

        // pack P -> bf16 A-operand (i = lane&15, j = 4g+(e&3)+16*(e>>2))
        bf16x8 pf;
#pragma unroll
        for (int e = 0; e < 8; ++e) pf[e] = (short)f2bf(p[e]);

        // ---- PV: O[i][c] += P[i][j] * v[c][j]^T over this 32-j tile ----
        {
            const bf16x8 vf0 = load8(&Vs[cur][li][4 * g],      &Vs[cur][li][16 + 4 * g]);
            o0 = __builtin_amdgcn_mfma_f32_16x16x32_bf16(pf, vf0, o0, 0, 0, 0);
            const bf16x8 vf1 = load8(&Vs[cur][16 + li][4 * g], &Vs[cur][16 + li][16 + 4 * g]);
            o1 = __builtin_amdgcn_mfma_f32_16x16x32_bf16(pf, vf1, o1, 0, 0, 0);
            const bf16x8 vf2 = load8(&Vs[cur][32 + li][4 * g], &Vs[cur][32 + li][16 + 4 * g]);
            o2 = __builtin_amdgcn_mfma_f32_16x16x32_bf16(pf, vf2, o2, 0, 0, 0);
            const bf16x8 vf3 = load8(&Vs[cur][48 + li][4 * g], &Vs[cur][48 + li][16 + 4 * g]);
            o3 = __builtin_amdgcn_mfma_f32_16x16x32_bf16(pf, vf3, o3, 0, 0, 0);
        }

        if (t < 63) {
            *(uint4*)&Ks[cur ^ 1][tid >> 3][(tid & 7) * 8] = kd;
            *(uint4*)&Vs[cur ^ 1][tid >> 2][(tid & 3) * 8] = vd;
        }
        __syncthreads();
    }

    // ---- epilogue: normalize, transpose through LDS, coalesced store ----
    const float linv = 1.0f / lsum;
#pragma unroll
    for (int r = 0; r < 4; ++r) {
        const float ir = __shfl(linv, 4 * g + r, 16);
        Os[w][4 * g + r][0 * 16 + li] = o0[r] * ir;
        Os[w][4 * g + r][1 * 16 + li] = o1[r] * ir;
        Os[w][4 * g + r][2 * 16 + li] = o2[r] * ir;
        Os[w][4 * g + r][3 * 16 + li] = o3[r] * ir;
    }
    __syncthreads();

    const int i0 = blki * 64 + w * 16;
    float* ob = out + ((size_t)bi * NC + l) * NN + i0;   // lane l -> channel c = l
    float tmp[16];
#pragma unroll
    for (int i = 0; i < 16; ++i) tmp[i] = Os[w][i][l];
#pragma unroll
    for (int i = 0; i < 16; i += 4) {
        float4 v4 = make_float4(tmp[i], tmp[i + 1], tmp[i + 2], tmp[i + 3]);
        *(float4*)(ob + i) = v4;
    }
}

// ---------------------------------------------------------------------------
extern "C" void kernel_launch(void* const* d_in, const int* in_sizes, int n_in,
                              void* d_out, int out_size, void* d_ws, size_t ws_size,
                              hipStream_t stream)
{
    const float* x  = (const float*)d_in[0];
    const float* wq = (const float*)d_in[1];
    const float* bq = (const float*)d_in[2];
    const float* wk = (const float*)d_in[3];
    const float* bk = (const float*)d_in[4];
    const float* wv = (const float*)d_in[5];
    const float* bv = (const float*)d_in[6];

    unsigned short* ws16 = (unsigned short*)d_ws;
    unsigned short* qT = ws16;                                  // [b][n][c] bf16, 2MB
    unsigned short* kT = ws16 + (size_t)BATCH * NN * NC;        // 2MB
    unsigned short* vv = ws16 + (size_t)2 * BATCH * NN * NC;    // [b][c][n], 2MB
    float* out = (float*)d_out;

    dim3 gridc(512, 1, 3);
    conv_qkv<<<gridc, 256, 0, stream>>>(x, wq, bq, wk, bk, wv, bv, qT, kT, vv);

    attn_mfma<<<dim3(256), 256, 0, stream>>>(qT, kT, vv, out);
}

// Round 4
// 81.064 us; speedup vs baseline: 6.0237x; 2.2564x over previous
//
#include <hip/hip_runtime.h>
#include <hip/hip_bf16.h>

#define BATCH 8
#define NC    64      // channels (Cin == Cout == 64)
#define HH    32
#define WW    64
#define NN    2048    // HH*WW
#define NCP   72      // padded ci slots per LDS row (144 B, 16B-aligned frags)

typedef __attribute__((ext_vector_type(8))) short bf16x8;
typedef __attribute__((ext_vector_type(4))) short short4v;
typedef __attribute__((ext_vector_type(4))) float f32x4;

__device__ __forceinline__ unsigned short f2bf(float f) {
    union { float f; unsigned u; } v; v.f = f;
    unsigned r = v.u + 0x7fffu + ((v.u >> 16) & 1u);   // RNE
    return (unsigned short)(r >> 16);
}

__device__ __forceinline__ bf16x8 load8(const unsigned short* a, const unsigned short* b) {
    short4v lo = *(const short4v*)a;
    short4v hi = *(const short4v*)b;
    return __builtin_shufflevector(lo, hi, 0, 1, 2, 3, 4, 5, 6, 7);
}

// slot j (0..63) -> original ci. Bits: [5]=h, [4:3]=g, [2]=t, [1:0]=e0
// ci = h*32 + t*16 + g*4 + e0. Both A and B operands use this same map, so
// MFMA dot products are unchanged (positional pairing).
__device__ __forceinline__ int ci_of_slot(int j) {
    return (j & 32) | (((j >> 2) & 1) << 4) | (((j >> 3) & 3) << 2) | (j & 3);
}

// ---------------------------------------------------------------------------
// prep_w: weights fp32 [cout][cin][3][3] -> wb bf16 [tap][row=conv*64+cout][slot]
// ---------------------------------------------------------------------------
__global__ __launch_bounds__(256) void prep_w(
    const float* __restrict__ wq, const float* __restrict__ wk,
    const float* __restrict__ wv, unsigned short* __restrict__ wb)
{
    const int idx = blockIdx.x * 256 + threadIdx.x;
    if (idx >= 9 * 192 * 64) return;
    const int j    = idx & 63;
    const int row  = (idx >> 6) % 192;
    const int tap  = idx / (192 * 64);
    const int ci   = ci_of_slot(j);
    const int conv = row >> 6;
    const int cout = row & 63;
    const float* ww = (conv == 0) ? wq : (conv == 1) ? wk : wv;
    wb[idx] = f2bf(ww[((size_t)cout * 64 + ci) * 9 + tap]);
}

// ---------------------------------------------------------------------------
// prep_x: x fp32 [b][ci][y][xx] -> xb bf16 [b][y][xx][slot]  (LDS transpose)
// ---------------------------------------------------------------------------
__global__ __launch_bounds__(256) void prep_x(
    const float* __restrict__ x, unsigned short* __restrict__ xb)
{
    __shared__ unsigned short T[64][72];   // [xx][ci]
    const int bi  = blockIdx.x >> 5;
    const int y   = blockIdx.x & 31;
    const int tid = threadIdx.x;

#pragma unroll
    for (int pass = 0; pass < 16; ++pass) {
        const int idx = pass * 256 + tid;          // 4096 elements
        const int ci = idx >> 6, xx = idx & 63;
        T[xx][ci] = f2bf(x[(((size_t)bi * 64 + ci) * 32 + y) * 64 + xx]);
    }
    __syncthreads();

#pragma unroll
    for (int pass = 0; pass < 2; ++pass) {
        const int chunk = pass * 256 + tid;        // 512 uint4 chunks
        const int xx = chunk >> 3, j8 = chunk & 7;
        unsigned short h[8];
#pragma unroll
        for (int e = 0; e < 8; ++e)
            h[e] = T[xx][ci_of_slot(j8 * 8 + e)];
        uint4 u;
        u.x = (unsigned)h[0] | ((unsigned)h[1] << 16);
        u.y = (unsigned)h[2] | ((unsigned)h[3] << 16);
        u.z = (unsigned)h[4] | ((unsigned)h[5] << 16);
        u.w = (unsigned)h[6] | ((unsigned)h[7] << 16);
        *(uint4*)(xb + ((((size_t)bi * 32 + y) * 64 + xx) * 64) + j8 * 8) = u;
    }
}

// ---------------------------------------------------------------------------
// conv_mfma: implicit-GEMM conv, all 3 convs fused (M = 192).
// Block = (batch, image row y): 4 waves; wave = (couthalf = w&1, pxpair = w>>1).
// 9 taps: per tap stage W_tap[192][slots] in LDS (prefetch next in regs),
// B operand = shifted reads from X tile [3 rows][66 cols][slots].
// ---------------------------------------------------------------------------
__global__ __launch_bounds__(256) void conv_mfma(
    const unsigned short* __restrict__ xb,   // [b][y][xx][slot]
    const unsigned short* __restrict__ wb,   // [tap][row][slot]
    const float* __restrict__ bq, const float* __restrict__ bk,
    const float* __restrict__ bv,
    unsigned short* __restrict__ qT,         // [b][n][c]
    unsigned short* __restrict__ kT,         // [b][n][c]
    unsigned short* __restrict__ vv)         // [b][c][n]
{
    __shared__ __align__(16) unsigned short Xs[3][66][NCP];  // 27.8 KB
    __shared__ __align__(16) unsigned short Ws[192][NCP];    // 27.6 KB

    const int bi  = blockIdx.x >> 5;
    const int y   = blockIdx.x & 31;
    const int tid = threadIdx.x;
    const int l   = tid & 63;
    const int w   = tid >> 6;
    const int g   = l >> 4;
    const int li  = l & 15;
    const int ch  = w & 1;        // couthalf: rows 96*ch .. 96*ch+95
    const int pp  = w >> 1;       // pixel pair: xx 32*pp .. 32*pp+31

    // ---- stage X tile: rows y-1..y+1, cols -1..64 (zero halo) ----
#pragma unroll
    for (int r = 0; r < 3; ++r) {
        const int yy = y + r - 1;
#pragma unroll
        for (int pass = 0; pass < 3; ++pass) {
            const int chunk = pass * 256 + tid;          // 528 chunks
            if (chunk >= 528) break;
            const int c = chunk >> 3, ci8 = chunk & 7;   // c: 0..65
            uint4 d = {0, 0, 0, 0};
            const int xx = c - 1;
            if (yy >= 0 && yy < HH && xx >= 0 && xx < WW)
                d = *(const uint4*)(xb + ((((size_t)bi * HH + yy) * WW + xx) * 64) + ci8 * 8);
            *(uint4*)&Xs[r][c][ci8 * 8] = d;
        }
    }
    // ---- stage W tap 0 ----
#pragma unroll
    for (int pass = 0; pass < 6; ++pass) {
        const int chunk = pass * 256 + tid;              // 1536 chunks
        const int row = chunk >> 3, ci8 = chunk & 7;
        uint4 d = *(const uint4*)(wb + ((size_t)row * 64) + ci8 * 8);
        *(uint4*)&Ws[row][ci8 * 8] = d;
    }
    __syncthreads();

    f32x4 acc[2][6];
#pragma unroll
    for (int p2 = 0; p2 < 2; ++p2)
#pragma unroll
        for (int ct = 0; ct < 6; ++ct) acc[p2][ct] = (f32x4){0, 0, 0, 0};

#pragma unroll
    for (int tap = 0; tap < 9; ++tap) {
        const int ky = tap / 3, kx = tap % 3;

        // prefetch next tap's W into regs (overlaps with compute)
        uint4 wd[6];
        if (tap < 8) {
#pragma unroll
            for (int pass = 0; pass < 6; ++pass) {
                const int chunk = pass * 256 + tid;
                const int row = chunk >> 3, ci8 = chunk & 7;
                wd[pass] = *(const uint4*)(wb + ((size_t)(tap + 1) * 192 + row) * 64 + ci8 * 8);
            }
        }

        // B fragments: pixel rows, shifted column reads
        bf16x8 xf[2][2];
#pragma unroll
        for (int p2 = 0; p2 < 2; ++p2) {
            const int c = (pp * 2 + p2) * 16 + li + kx;   // 0..65
            xf[p2][0] = *(const bf16x8*)&Xs[ky][c][g * 8];
            xf[p2][1] = *(const bf16x8*)&Xs[ky][c][32 + g * 8];
        }

        // A fragments + MFMAs
#pragma unroll
        for (int ct = 0; ct < 6; ++ct) {
            const int row = ch * 96 + ct * 16 + li;
            const bf16x8 wf0 = *(const bf16x8*)&Ws[row][g * 8];
            const bf16x8 wf1 = *(const bf16x8*)&Ws[row][32 + g * 8];
            acc[0][ct] = __builtin_amdgcn_mfma_f32_16x16x32_bf16(wf0, xf[0][0], acc[0][ct], 0, 0, 0);
            acc[0][ct] = __builtin_amdgcn_mfma_f32_16x16x32_bf16(wf1, xf[0][1], acc[0][ct], 0, 0, 0);
            acc[1][ct] = __builtin_amdgcn_mfma_f32_16x16x32_bf16(wf0, xf[1][0], acc[1][ct], 0, 0, 0);
            acc[1][ct] = __builtin_amdgcn_mfma_f32_16x16x32_bf16(wf1, xf[1][1], acc[1][ct], 0, 0, 0);
        }
        __syncthreads();
        if (tap < 8) {
#pragma unroll
            for (int pass = 0; pass < 6; ++pass) {
                const int chunk = pass * 256 + tid;
                const int row = chunk >> 3, ci8 = chunk & 7;
                *(uint4*)&Ws[row][ci8 * 8] = wd[pass];
            }
            __syncthreads();
        }
    }

    // ---- epilogue: bias + store. D: m = 4g+r (cout row), n = li (pixel) ----
#pragma unroll
    for (int p2 = 0; p2 < 2; ++p2) {
        const int n = y * 64 + pp * 32 + p2 * 16 + li;
#pragma unroll
        for (int ct = 0; ct < 6; ++ct) {
            const int rowbase = ch * 96 + ct * 16 + 4 * g;   // conv const over r=0..3
            const int conv  = rowbase >> 6;
            const int cout0 = rowbase & 63;
            const float* bias = (conv == 0) ? bq : (conv == 1) ? bk : bv;
            float v0 = acc[p2][ct][0] + bias[cout0 + 0];
            float v1 = acc[p2][ct][1] + bias[cout0 + 1];
            float v2 = acc[p2][ct][2] + bias[cout0 + 2];
            float v3 = acc[p2][ct][3] + bias[cout0 + 3];
            if (conv < 2) {
                uint2 pk;
                pk.x = (unsigned)f2bf(v0) | ((unsigned)f2bf(v1) << 16);
                pk.y = (unsigned)f2bf(v2) | ((unsigned)f2bf(v3) << 16);
                unsigned short* dst = ((conv == 0) ? qT : kT) +
                                      ((size_t)bi * NN + n) * NC + cout0;
                *(uint2*)dst = pk;
            } else {
                vv[((size_t)bi * NC + cout0 + 0) * NN + n] = f2bf(v0);
                vv[((size_t)bi * NC + cout0 + 1) * NN + n] = f2bf(v1);
                vv[((size_t)bi * NC + cout0 + 2) * NN + n] = f2bf(v2);
                vv[((size_t)bi * NC + cout0 + 3) * NN + n] = f2bf(v3);
            }
        }
    }
}

// ---------------------------------------------------------------------------
// Kernel: bf16 MFMA flash attention (unchanged from round 3 — passed at ~30us).
// ---------------------------------------------------------------------------
__global__ __launch_bounds__(256) void attn_mfma(
    const unsigned short* __restrict__ qT,  // [b][n][c]
    const unsigned short* __restrict__ kT,  // [b][n][c]
    const unsigned short* __restrict__ vv,  // [b][c][n]
    float* __restrict__ out)                // [b][c][n]
{
    __shared__ __align__(16) unsigned short Qs[64][72];
    __shared__ __align__(16) unsigned short Ks[2][32][72];
    __shared__ __align__(16) unsigned short Vs[2][64][40];
    __shared__ __align__(16) float Os[4][16][66];

    const int bi   = blockIdx.x >> 5;    // batch
    const int blki = blockIdx.x & 31;    // 64-row tile within batch
    const int tid  = threadIdx.x;
    const int l    = tid & 63;
    const int w    = tid >> 6;
    const int g    = l >> 4;
    const int li   = l & 15;

    const unsigned short* qb = qT + (size_t)bi * NN * NC;
    const unsigned short* kb = kT + (size_t)bi * NN * NC;
    const unsigned short* vb = vv + (size_t)bi * NC * NN;

    // ---- stage Q tile (64 rows x 64 c) ----
    {
        const int r0 = tid >> 3;        // 0..31
        const int chv = tid & 7;
#pragma unroll
        for (int pass = 0; pass < 2; ++pass) {
            const int r = pass * 32 + r0;
            uint4 d = *(const uint4*)(qb + ((size_t)(blki * 64 + r)) * NC + chv * 8);
            *(uint4*)&Qs[r][chv * 8] = d;
        }
    }

    // ---- prologue: stage j-tile 0 ----
    uint4 kd, vd;
    {
        kd = *(const uint4*)(kb + ((size_t)(tid >> 3)) * NC + (tid & 7) * 8);
        vd = *(const uint4*)(vb + (size_t)(tid >> 2) * NN + (tid & 3) * 8);
        *(uint4*)&Ks[0][tid >> 3][(tid & 7) * 8] = kd;
        *(uint4*)&Vs[0][tid >> 2][(tid & 3) * 8] = vd;
    }
    __syncthreads();

    // ---- Q fragments (hoisted) ----
    const int qrow = w * 16 + li;
    const bf16x8 qf0 = load8(&Qs[qrow][4 * g],      &Qs[qrow][16 + 4 * g]);
    const bf16x8 qf1 = load8(&Qs[qrow][32 + 4 * g], &Qs[qrow][48 + 4 * g]);

    f32x4 o0 = {0,0,0,0}, o1 = {0,0,0,0}, o2 = {0,0,0,0}, o3 = {0,0,0,0};
    float m = -1e30f, lsum = 0.0f;

    for (int t = 0; t < 64; ++t) {
        const int cur = t & 1;
        if (t < 63) {
            const int j0 = (t + 1) * 32;
            kd = *(const uint4*)(kb + ((size_t)(j0 + (tid >> 3))) * NC + (tid & 7) * 8);
            vd = *(const uint4*)(vb + (size_t)(tid >> 2) * NN + j0 + (tid & 3) * 8);
        }

        // K fragments (rows = j within tile)
        const bf16x8 kf00 = load8(&Ks[cur][li][4 * g],           &Ks[cur][li][16 + 4 * g]);
        const bf16x8 kf01 = load8(&Ks[cur][li][32 + 4 * g],      &Ks[cur][li][48 + 4 * g]);
        const bf16x8 kf10 = load8(&Ks[cur][16 + li][4 * g],      &Ks[cur][16 + li][16 + 4 * g]);
        const bf16x8 kf11 = load8(&Ks[cur][16 + li][32 + 4 * g], &Ks[cur][16 + li][48 + 4 * g]);

        const f32x4 z = {0,0,0,0};
        f32x4 d0 = __builtin_amdgcn_mfma_f32_16x16x32_bf16(kf00, qf0, z, 0, 0, 0);
        d0       = __builtin_amdgcn_mfma_f32_16x16x32_bf16(kf01, qf1, d0, 0, 0, 0);
        f32x4 d1 = __builtin_amdgcn_mfma_f32_16x16x32_bf16(kf10, qf0, z, 0, 0, 0);
        d1       = __builtin_amdgcn_mfma_f32_16x16x32_bf16(kf11, qf1, d1, 0, 0, 0);

        // ---- online softmax (row i = lane&15 is lane-local) ----
        float pmax = fmaxf(fmaxf(fmaxf(d0[0], d0[1]), fmaxf(d0[2], d0[3])),
                           fmaxf(fmaxf(d1[0], d1[1]), fmaxf(d1[2], d1[3])));
        pmax = fmaxf(pmax, __shfl_xor(pmax, 16));
        pmax = fmaxf(pmax, __shfl_xor(pmax, 32));
        const float mn = fmaxf(m, pmax);
        const float alpha = __expf(m - mn);
        m = mn;

        float p[8];
#pragma unroll
        for (int e = 0; e < 4; ++e) {
            p[e]     = __expf(d0[e] - mn);
            p[4 + e] = __expf(d1[e] - mn);
        }
        float ls = ((p[0] + p[1]) + (p[2] + p[3])) + ((p[4] + p[5]) + (p[6] + p[7]));
        ls += __shfl_xor(ls, 16);
        ls += __shfl_xor(ls, 32);
        lsum = lsum * alpha + ls;

        // rescale O (O rows are i = 4g+r -> fetch alpha for that row)
#pragma unroll
        for (int r = 0; r < 4; ++r) {
            const float ar = __shfl(alpha, 4 * g + r, 16);
            o0[r] *= ar; o1[r] *= ar; o2[r] *= ar; o3[r] *= ar;
        }

        // pack P -> bf16 A-operand (i = lane&15, j = 4g+(e&3)+16*(e>>2))
        bf16x8 pf;
#pragma unroll
        for (int e = 0; e < 8; ++e) pf[e] = (short)f2bf(p[e]);

        // ---- PV: O[i][c] += P[i][j] * v[c][j]^T over this 32-j tile ----
        {
            const bf16x8 vf0 = load8(&Vs[cur][li][4 * g],      &Vs[cur][li][16 + 4 * g]);
            o0 = __builtin_amdgcn_mfma_f32_16x16x32_bf16(pf, vf0, o0, 0, 0, 0);
            const bf16x8 vf1 = load8(&Vs[cur][16 + li][4 * g], &Vs[cur][16 + li][16 + 4 * g]);
            o1 = __builtin_amdgcn_mfma_f32_16x16x32_bf16(pf, vf1, o1, 0, 0, 0);
            const bf16x8 vf2 = load8(&Vs[cur][32 + li][4 * g], &Vs[cur][32 + li][16 + 4 * g]);
            o2 = __builtin_amdgcn_mfma_f32_16x16x32_bf16(pf, vf2, o2, 0, 0, 0);
            const bf16x8 vf3 = load8(&Vs[cur][48 + li][4 * g], &Vs[cur][48 + li][16 + 4 * g]);
            o3 = __builtin_amdgcn_mfma_f32_16x16x32_bf16(pf, vf3, o3, 0, 0, 0);
        }

        if (t < 63) {
            *(uint4*)&Ks[cur ^ 1][tid >> 3][(tid & 7) * 8] = kd;
            *(uint4*)&Vs[cur ^ 1][tid >> 2][(tid & 3) * 8] = vd;
        }
        __syncthreads();
    }

    // ---- epilogue: normalize, transpose through LDS, coalesced store ----
    const float linv = 1.0f / lsum;
#pragma unroll
    for (int r = 0; r < 4; ++r) {
        const float ir = __shfl(linv, 4 * g + r, 16);
        Os[w][4 * g + r][0 * 16 + li] = o0[r] * ir;
        Os[w][4 * g + r][1 * 16 + li] = o1[r] * ir;
        Os[w][4 * g + r][2 * 16 + li] = o2[r] * ir;
        Os[w][4 * g + r][3 * 16 + li] = o3[r] * ir;
    }
    __syncthreads();

    const int i0 = blki * 64 + w * 16;
    float* ob = out + ((size_t)bi * NC + l) * NN + i0;   // lane l -> channel c = l
    float tmp[16];
#pragma unroll
    for (int i = 0; i < 16; ++i) tmp[i] = Os[w][i][l];
#pragma unroll
    for (int i = 0; i < 16; i += 4) {
        float4 v4 = make_float4(tmp[i], tmp[i + 1], tmp[i + 2], tmp[i + 3]);
        *(float4*)(ob + i) = v4;
    }
}

// ---------------------------------------------------------------------------
extern "C" void kernel_launch(void* const* d_in, const int* in_sizes, int n_in,
                              void* d_out, int out_size, void* d_ws, size_t ws_size,
                              hipStream_t stream)
{
    const float* x  = (const float*)d_in[0];
    const float* wq = (const float*)d_in[1];
    const float* bq = (const float*)d_in[2];
    const float* wk = (const float*)d_in[3];
    const float* bk = (const float*)d_in[4];
    const float* wv = (const float*)d_in[5];
    const float* bv = (const float*)d_in[6];

    unsigned short* ws16 = (unsigned short*)d_ws;
    unsigned short* qT = ws16;                                   // [b][n][c] 2MB
    unsigned short* kT = ws16 + (size_t)BATCH * NN * NC;         // 2MB
    unsigned short* vv = ws16 + (size_t)2 * BATCH * NN * NC;     // [b][c][n] 2MB
    unsigned short* xb = ws16 + (size_t)3 * BATCH * NN * NC;     // [b][y][xx][slot] 2MB
    unsigned short* wb = ws16 + (size_t)4 * BATCH * NN * NC;     // [tap][192][64] 216KB
    float* out = (float*)d_out;

    prep_w<<<dim3(432), 256, 0, stream>>>(wq, wk, wv, wb);
    prep_x<<<dim3(256), 256, 0, stream>>>(x, xb);
    conv_mfma<<<dim3(256), 256, 0, stream>>>(xb, wb, bq, bk, bv, qT, kT, vv);
    attn_mfma<<<dim3(256), 256, 0, stream>>>(qT, kT, vv, out);
}